// Round 10
// baseline (8531.811 us; speedup 1.0000x reference)
//
#include <hip/hip_runtime.h>

// Problem constants
#define Bn 4
#define Ln 256
#define Dn 256
#define Wn 8
#define NBLK 64          // 16 blocks per batch, 64 total (all co-resident on 256 CUs)
#define BLD (Bn*Ln*Dn)   // 262144
#define BDD (Bn*Dn*Dn)   // 262144

typedef float  floatx4 __attribute__((ext_vector_type(4)));
typedef short  short8  __attribute__((ext_vector_type(8)));

// -------------------------------------------------------------------------
// Coherent (cross-XCD) access helpers: sc0 sc1 bypass L1/L2, live at MALL
// -------------------------------------------------------------------------
__device__ __forceinline__ void stc(float* p, float v) {
    __hip_atomic_store(p, v, __ATOMIC_RELAXED, __HIP_MEMORY_SCOPE_AGENT);
}
__device__ __forceinline__ void stc4(float* p, floatx4 v) {
    asm volatile("global_store_dwordx4 %0, %1, off sc0 sc1" :: "v"(p), "v"(v) : "memory");
}
__device__ __forceinline__ void ldc1x4(float& a, float& b, float& c, float& d,
    const float* p0, const float* p1, const float* p2, const float* p3)
{
    asm volatile(
        "global_load_dword %0, %4, off sc0 sc1\n\t"
        "global_load_dword %1, %5, off sc0 sc1\n\t"
        "global_load_dword %2, %6, off sc0 sc1\n\t"
        "global_load_dword %3, %7, off sc0 sc1\n\t"
        "s_waitcnt vmcnt(0)"
        : "=&v"(a), "=&v"(b), "=&v"(c), "=&v"(d)
        : "v"(p0), "v"(p1), "v"(p2), "v"(p3)
        : "memory");
}
// 16 b128 loads (8 bases, each +0 and +16B), single waitcnt: ONE MALL round trip
__device__ __forceinline__ void ldc4x16o(
    floatx4& e00, floatx4& e01, floatx4& e10, floatx4& e11,
    floatx4& e20, floatx4& e21, floatx4& e30, floatx4& e31,
    floatx4& q00, floatx4& q01, floatx4& q10, floatx4& q11,
    floatx4& q20, floatx4& q21, floatx4& q30, floatx4& q31,
    const float* pe0, const float* pe1, const float* pe2, const float* pe3,
    const float* pq0, const float* pq1, const float* pq2, const float* pq3)
{
    asm volatile(
        "global_load_dwordx4 %0, %16, off sc0 sc1\n\t"
        "global_load_dwordx4 %1, %16, off offset:16 sc0 sc1\n\t"
        "global_load_dwordx4 %2, %17, off sc0 sc1\n\t"
        "global_load_dwordx4 %3, %17, off offset:16 sc0 sc1\n\t"
        "global_load_dwordx4 %4, %18, off sc0 sc1\n\t"
        "global_load_dwordx4 %5, %18, off offset:16 sc0 sc1\n\t"
        "global_load_dwordx4 %6, %19, off sc0 sc1\n\t"
        "global_load_dwordx4 %7, %19, off offset:16 sc0 sc1\n\t"
        "global_load_dwordx4 %8, %20, off sc0 sc1\n\t"
        "global_load_dwordx4 %9, %20, off offset:16 sc0 sc1\n\t"
        "global_load_dwordx4 %10, %21, off sc0 sc1\n\t"
        "global_load_dwordx4 %11, %21, off offset:16 sc0 sc1\n\t"
        "global_load_dwordx4 %12, %22, off sc0 sc1\n\t"
        "global_load_dwordx4 %13, %22, off offset:16 sc0 sc1\n\t"
        "global_load_dwordx4 %14, %23, off sc0 sc1\n\t"
        "global_load_dwordx4 %15, %23, off offset:16 sc0 sc1\n\t"
        "s_waitcnt vmcnt(0)"
        : "=&v"(e00), "=&v"(e01), "=&v"(e10), "=&v"(e11),
          "=&v"(e20), "=&v"(e21), "=&v"(e30), "=&v"(e31),
          "=&v"(q00), "=&v"(q01), "=&v"(q10), "=&v"(q11),
          "=&v"(q20), "=&v"(q21), "=&v"(q30), "=&v"(q31)
        : "v"(pe0), "v"(pe1), "v"(pe2), "v"(pe3),
          "v"(pq0), "v"(pq1), "v"(pq2), "v"(pq3)
        : "memory");
}

// bf16 pack (RNE)
__device__ __forceinline__ unsigned f2bf(float x) {
    unsigned u = __float_as_uint(x);
    return (u + 0x7FFFu + ((u >> 16) & 1u)) >> 16;
}
__device__ __forceinline__ unsigned long long packbf4(floatx4 v) {
    unsigned lo = f2bf(v[0]) | (f2bf(v[1]) << 16);
    unsigned hi = f2bf(v[2]) | (f2bf(v[3]) << 16);
    return (unsigned long long)lo | ((unsigned long long)hi << 32);
}
union BF8 { short8 s8; unsigned long long u[2]; };

// -------------------------------------------------------------------------
// fence-free PER-BATCH barrier (16 blocks) [verified rounds 8-9]
// -------------------------------------------------------------------------
__device__ __forceinline__ void grid_sync_b(unsigned* bflags, int rem, unsigned k)
{
    asm volatile("s_waitcnt vmcnt(0) lgkmcnt(0)" ::: "memory");
    __syncthreads();
    if (threadIdx.x == 0)
        __hip_atomic_store(&bflags[rem * 32], k,
                           __ATOMIC_RELAXED, __HIP_MEMORY_SCOPE_AGENT);
    if (threadIdx.x < 16) {
        while (__hip_atomic_load(&bflags[threadIdx.x * 32],
                                 __ATOMIC_RELAXED, __HIP_MEMORY_SCOPE_AGENT) < k)
            __builtin_amdgcn_s_sleep(1);
    }
    __syncthreads();
}

// -------------------------------------------------------------------------
// kphi + gamma    [verified round 2]
// -------------------------------------------------------------------------
__global__ __launch_bounds__(256) void kphi_gamma_kernel(
    const float* __restrict__ k_al, const float* __restrict__ x,
    const float* __restrict__ poly, const float* __restrict__ gW,
    const float* __restrict__ gb, float* __restrict__ kphi,
    float* __restrict__ gamma)
{
    int wg = blockIdx.x, tid = threadIdx.x;
    int wave = tid >> 6, lane = tid & 63;
    int n = wg * 4 + wave;
    float gacc = 0.f;
#pragma unroll
    for (int c = 0; c < 4; ++c) {
        int e = lane + 64 * c;
        float kv = k_al[n * Dn + e];
        kphi[n * Dn + e] = poly[e] * kv + poly[Dn + e] * kv * kv;
        gacc += x[n * Dn + e] * gW[e];
    }
#pragma unroll
    for (int off = 32; off; off >>= 1) gacc += __shfl_xor(gacc, off);
    if (lane == 0) gamma[n] = 1.f / (1.f + expf(-(gacc + gb[0])));
}

// -------------------------------------------------------------------------
// tiled GEMM  [verified round 2]
// -------------------------------------------------------------------------
template <int ACT>
__global__ __launch_bounds__(256) void gemm_act_kernel(
    const float* __restrict__ In, const float* __restrict__ Wm,
    const float* __restrict__ bias, float* __restrict__ Out)
{
    __shared__ float ldsX[32 * 64];
    __shared__ float ldsW[64 * 65];
    int n0 = blockIdx.x * 32;
    int m0 = blockIdx.y * 64;
    int tid = threadIdx.x;
    float acc[8] = {0, 0, 0, 0, 0, 0, 0, 0};
    for (int j0 = 0; j0 < 256; j0 += 64) {
#pragma unroll
        for (int q = 0; q < 2; ++q) {
            int fi = tid + 256 * q; int row = fi >> 4; int c4 = (fi & 15) << 2;
            *(float4*)&ldsX[row * 64 + c4] =
                *(const float4*)&In[(n0 + row) * 256 + j0 + c4];
        }
#pragma unroll
        for (int q = 0; q < 4; ++q) {
            int fi = tid + 256 * q; int row = fi >> 4; int c4 = (fi & 15) << 2;
            float4 vv = *(const float4*)&Wm[(m0 + row) * 256 + j0 + c4];
            ldsW[(c4 + 0) * 65 + row] = vv.x;
            ldsW[(c4 + 1) * 65 + row] = vv.y;
            ldsW[(c4 + 2) * 65 + row] = vv.z;
            ldsW[(c4 + 3) * 65 + row] = vv.w;
        }
        __syncthreads();
        int m = tid & 63, ng = tid >> 6;
        for (int j = 0; j < 64; ++j) {
            float wv = ldsW[j * 65 + m];
#pragma unroll
            for (int r = 0; r < 8; ++r) acc[r] += ldsX[(ng * 8 + r) * 64 + j] * wv;
        }
        __syncthreads();
    }
    int m = tid & 63, ng = tid >> 6;
    float bv = bias[m0 + m];
#pragma unroll
    for (int r = 0; r < 8; ++r) {
        float vv = acc[r] + bv;
        if (ACT == 1) vv = 1.f / (1.f + expf(-vv));
        if (ACT == 2) vv = 0.1f / (1.f + expf(-vv));
        Out[(n0 + ng * 8 + r) * 256 + m0 + m] = vv;
    }
}

// -------------------------------------------------------------------------
// K-gram precompute   [verified round 8]
// -------------------------------------------------------------------------
__global__ __launch_bounds__(64) void kgram_kernel(
    const float* __restrict__ kphi, float* __restrict__ Kall)
{
    int t = blockIdx.x, b = blockIdx.y, tid = threadIdx.x;
    int wa = tid >> 3, wb = tid & 7;
    int ta = t - 7 + wa, tb = t - 7 + wb;
    float g = 0.f;
    if (ta >= 0 && tb >= 0) {
        const float* pa = &kphi[(b * Ln + ta) * Dn];
        const float* pb = &kphi[(b * Ln + tb) * Dn];
        for (int j = 0; j < Dn; j += 4) {
            floatx4 x1 = *(const floatx4*)&pa[j];
            floatx4 x2 = *(const floatx4*)&pb[j];
            g += x1[0]*x2[0] + x1[1]*x2[1] + x1[2]*x2[2] + x1[3]*x2[3];
        }
    }
    Kall[(b * Ln + t) * 64 + tid] = g;
}

// -------------------------------------------------------------------------
// prologue: zero barrier flags
// -------------------------------------------------------------------------
__global__ __launch_bounds__(256) void prologue_kernel(unsigned* __restrict__ flags)
{
    int gidx = blockIdx.x * 256 + threadIdx.x;
    if (gidx < 512) {
        uint4 zu = {0u, 0u, 0u, 0u};
        ((uint4*)flags)[gidx] = zu;
    }
}

// -------------------------------------------------------------------------
// ysum: fold 4 l0-slot partials of y into slot 0
// -------------------------------------------------------------------------
__global__ __launch_bounds__(256) void ysum_kernel(float* __restrict__ ysp)
{
    int gidx = blockIdx.x * 256 + threadIdx.x;
    float4 a = ((float4*)ysp)[gidx];
    float4 b = ((float4*)ysp)[65536 + gidx];
    float4 c = ((float4*)ysp)[131072 + gidx];
    float4 d = ((float4*)ysp)[196608 + gidx];
    a.x += b.x + c.x + d.x;
    a.y += b.y + c.y + d.y;
    a.z += b.z + c.z + d.z;
    a.w += b.w + c.w + d.w;
    ((float4*)ysp)[gidx] = a;
}

// -------------------------------------------------------------------------
// Persistent scan, SINGLE-PHASE: 64 blocks x 256 threads. Block (b, rem):
//  owns M tile (regs), T panel (regs, A-frag), S columns [all d][l0-range]
//  (LDS fp32 + bf16 mirror), rowsq recurrence for the norm (no exchange).
//  Per step: 1 batched exchange read (err+q partials) + 1 barrier.
// -------------------------------------------------------------------------
#define OFF_SCOL 0        // fp32 [64 e][260 d] = 16640 (also init scratch)
#define OFF_STBF 16640    // bf16 [64 e][264 d] swizzled = 8448 floats
#define OFF_UV   25088    // [8][260]
#define OFF_QV   27168    // [8][260]
#define OFF_CV   29248    // [8][260]
#define OFF_TH   31328    // [256]
#define OFF_KWA  31584    // [8][260]
#define OFF_KNX  33664    // [260]
#define OFF_KL   33924    // [64]
#define OFF_RED  33988    // [8]
#define SMEM_FLOATS 34000 // 136 KB

__global__ void __launch_bounds__(256, 1) scan_kernel(
    const float* __restrict__ kphi, const float* __restrict__ vin,
    const float* __restrict__ gammaB, const float* __restrict__ alphaB,
    const float* __restrict__ etaB, const float* __restrict__ thetaB,
    const float* __restrict__ Kall,
    const float* __restrict__ Mprev, const float* __restrict__ Sprev,
    float* __restrict__ errp, float* __restrict__ qp,
    float* __restrict__ rsqp, float* __restrict__ ysp,
    unsigned* __restrict__ flags,
    float* __restrict__ outM, float* __restrict__ outS)
{
    __shared__ float smem[SMEM_FLOATS];
    float* Scol  = smem + OFF_SCOL;
    char*  STbB  = (char*)(smem + OFF_STBF);
    float* uv    = smem + OFF_UV;
    float* qv    = smem + OFF_QV;
    float* cv    = smem + OFF_CV;
    float* thv   = smem + OFF_TH;
    float* kWA   = smem + OFF_KWA;
    float* kNext = smem + OFF_KNX;
    float* Kl    = smem + OFF_KL;
    float* red   = smem + OFF_RED;

    const int wg = blockIdx.x, tid = threadIdx.x;
    const int b   = wg >> 4;
    const int rem = wg & 15;
    const int s   = rem & 3;                               // l0-slot
    const int i0 = (rem >> 2) * 64, l0 = (rem & 3) * 64;
    const int wid = tid >> 6, lane = tid & 63;
    const int lme = lane & 15, hi = lane >> 4;
    const int ibr = i0 + wid * 16 + (hi << 2);
    unsigned* bflags = flags + b * 512;
    unsigned kbar = 0;

    float   M_reg[16];   // M[ibr+g][l0+lt*16+lme]
    floatx4 T_reg[16];   // T[wid*16+lme][kc*32+hi*8 ..] (MFMA A-frag)
    float   rowsq_r;     // ||S[d=tid,:]||^2 recurrence

    // =========================== INIT ===========================
    {
#pragma unroll
        for (int lt = 0; lt < 4; ++lt)
#pragma unroll
            for (int g = 0; g < 4; ++g)
                M_reg[lt*4+g] = Mprev[(size_t)(b*256 + ibr + g)*256 + l0 + lt*16 + lme];

        // T panel = Sprev Sprev^T rows [i0,i0+64) (bf16 MFMA) -> scratch -> regs
        float* scratch = smem;   // [64][260], init-only alias of Scol
        for (int g4 = 0; g4 < 4; ++g4) {
            floatx4 acc[4];
#pragma unroll
            for (int lt = 0; lt < 4; ++lt) acc[lt] = (floatx4){0.f,0.f,0.f,0.f};
#pragma unroll
            for (int kc = 0; kc < 8; ++kc) {
                int kb2 = kc*32 + hi*8;
                floatx4 a0 = *(const floatx4*)&Sprev[(size_t)(b*256 + i0 + wid*16 + lme)*256 + kb2];
                floatx4 a1 = *(const floatx4*)&Sprev[(size_t)(b*256 + i0 + wid*16 + lme)*256 + kb2 + 4];
                BF8 ua; ua.u[0] = packbf4(a0); ua.u[1] = packbf4(a1);
#pragma unroll
                for (int lt = 0; lt < 4; ++lt) {
                    int brow = g4*64 + lt*16 + lme;
                    floatx4 b0 = *(const floatx4*)&Sprev[(size_t)(b*256 + brow)*256 + kb2];
                    floatx4 b1 = *(const floatx4*)&Sprev[(size_t)(b*256 + brow)*256 + kb2 + 4];
                    BF8 ub; ub.u[0] = packbf4(b0); ub.u[1] = packbf4(b1);
                    acc[lt] = __builtin_amdgcn_mfma_f32_16x16x32_bf16(ua.s8, ub.s8, acc[lt], 0,0,0);
                }
            }
#pragma unroll
            for (int lt = 0; lt < 4; ++lt)
#pragma unroll
                for (int g = 0; g < 4; ++g)
                    scratch[(wid*16 + (hi<<2) + g)*260 + g4*64 + lt*16 + lme] = acc[lt][g];
        }
        __syncthreads();
#pragma unroll
        for (int kc = 0; kc < 8; ++kc) {
            T_reg[kc*2+0] = *(floatx4*)&scratch[(wid*16 + lme)*260 + kc*32 + hi*8];
            T_reg[kc*2+1] = *(floatx4*)&scratch[(wid*16 + lme)*260 + kc*32 + hi*8 + 4];
        }
        __syncthreads();

        // Fill S columns + bf16 mirror: Scol[e][d] = Sprev[d][l0+e], d = tid
        {
#pragma unroll
            for (int c = 0; c < 16; ++c) {
                floatx4 sv = *(const floatx4*)&Sprev[(size_t)(b*256 + tid)*256 + l0 + c*4];
#pragma unroll
                for (int j = 0; j < 4; ++j) {
                    int e = c*4 + j;
                    Scol[e*260 + tid] = sv[j];
                    *(unsigned short*)(STbB +
                        (((size_t)e*528 + 2*(size_t)tid) ^ (unsigned)((e&8)<<1))) =
                        (unsigned short)f2bf(sv[j]);
                }
            }
        }
        // stage window(0) + theta(0) + Kl(0)
        {
#pragma unroll
            for (int qq = 0; qq < 2; ++qq) {
                int idx = qq*256 + tid;
                int w = idx >> 6, c4 = (idx & 63) * 4;
                floatx4 kv = {0,0,0,0};
                int tk = 0 - 7 + w;
                if (tk >= 0) kv = *(const floatx4*)&kphi[(size_t)(b*Ln + tk)*Dn + c4];
                *(floatx4*)&kWA[w*260 + c4] = kv;
            }
        }
        __syncthreads();

        // rowsq partial over l0 e-range (only i0==0 group stores)
        if ((rem >> 2) == 0) {
            float sq = 0.f;
            for (int e = 0; e < 64; ++e) { float sv = Scol[e*260 + tid]; sq += sv*sv; }
            stc(&rsqp[(s*Bn + b)*256 + tid], sq);
        }
        // t=0 err partials (window0: only w=7 nonzero), parity 0
#pragma unroll
        for (int w = 0; w < 8; ++w) {
            float pd[4] = {0.f,0.f,0.f,0.f};
#pragma unroll
            for (int lt = 0; lt < 4; ++lt) {
                float kv2 = kWA[w*260 + l0 + lt*16 + lme];
#pragma unroll
                for (int g = 0; g < 4; ++g) pd[g] += M_reg[lt*4+g] * kv2;
            }
#pragma unroll
            for (int g = 0; g < 4; ++g) {
                pd[g] += __shfl_xor(pd[g], 1); pd[g] += __shfl_xor(pd[g], 2);
                pd[g] += __shfl_xor(pd[g], 4); pd[g] += __shfl_xor(pd[g], 8);
            }
            if (lme == 0) {
                floatx4 pv = {pd[0], pd[1], pd[2], pd[3]};
                stc4(&errp[(size_t)((s*2 + 0)*4 + b)*2048 + w*256 + ibr], pv);
            }
        }
        // t=0 q partials (Scol = Sprev, window0), parity 0
        {
            int dq = i0 + (tid >> 2), eq0 = (tid & 3) * 16;
            float qpd[8] = {0,0,0,0,0,0,0,0};
            for (int j = 0; j < 16; ++j) {
                float sv = Scol[(eq0 + j)*260 + dq];
#pragma unroll
                for (int w = 0; w < 8; ++w) qpd[w] += sv * kWA[w*260 + l0 + eq0 + j];
            }
#pragma unroll
            for (int w = 0; w < 8; ++w) {
                qpd[w] += __shfl_xor(qpd[w], 1); qpd[w] += __shfl_xor(qpd[w], 2);
            }
            if ((tid & 3) == 0)
#pragma unroll
                for (int w = 0; w < 8; ++w)
                    stc(&qp[(size_t)((s*2 + 0)*4 + b)*2048 + w*256 + dq], qpd[w]);
        }
        grid_sync_b(bflags, rem, ++kbar);
        // assemble rowsq
        {
            float r0, r1, r2, r3;
            ldc1x4(r0, r1, r2, r3,
                   &rsqp[(0*Bn + b)*256 + tid], &rsqp[(1*Bn + b)*256 + tid],
                   &rsqp[(2*Bn + b)*256 + tid], &rsqp[(3*Bn + b)*256 + tid]);
            rowsq_r = r0 + r1 + r2 + r3;
        }
    }

    for (int t = 0; t < Ln; ++t) {
        const int cwin = (t + 1 < Wn) ? (t + 1) : Wn;
        const float invc = 1.f / (float)cwin;
        const int p = t & 1;

        // ---- L1: stage window(t), kNext(t+1), theta(t), K(t)  (cached)
        {
#pragma unroll
            for (int qq = 0; qq < 2; ++qq) {
                int idx = qq*256 + tid;
                int w = idx >> 6, c4 = (idx & 63) * 4;
                floatx4 kv = {0,0,0,0};
                int tk = t - 7 + w;
                if (tk >= 0) kv = *(const floatx4*)&kphi[(size_t)(b*Ln + tk)*Dn + c4];
                *(floatx4*)&kWA[w*260 + c4] = kv;
            }
            if (tid < 64) {
                floatx4 kv = {0,0,0,0};
                if (t + 1 < Ln) kv = *(const floatx4*)&kphi[(size_t)(b*Ln + t + 1)*Dn + tid*4];
                *(floatx4*)&kNext[tid*4] = kv;
                *(floatx4*)&thv[tid*4] = *(const floatx4*)&thetaB[(size_t)(b*Ln + t)*Dn + tid*4];
            }
            if (tid < 16)
                *(floatx4*)&Kl[tid*4] = *(const floatx4*)&Kall[(size_t)(b*Ln + t)*64 + tid*4];
        }
        // ---- L2: ONE exchange round trip (err + q, 4 slots each), u/q to LDS
        {
            const int wX = tid >> 5;
            const int dX = (tid & 31) * 8;
            const float* pe0 = errp + (size_t)((0*2 + p)*4 + b)*2048 + wX*256 + dX;
            const float* pe1 = errp + (size_t)((1*2 + p)*4 + b)*2048 + wX*256 + dX;
            const float* pe2 = errp + (size_t)((2*2 + p)*4 + b)*2048 + wX*256 + dX;
            const float* pe3 = errp + (size_t)((3*2 + p)*4 + b)*2048 + wX*256 + dX;
            const float* pq0 = qp   + (size_t)((0*2 + p)*4 + b)*2048 + wX*256 + dX;
            const float* pq1 = qp   + (size_t)((1*2 + p)*4 + b)*2048 + wX*256 + dX;
            const float* pq2 = qp   + (size_t)((2*2 + p)*4 + b)*2048 + wX*256 + dX;
            const float* pq3 = qp   + (size_t)((3*2 + p)*4 + b)*2048 + wX*256 + dX;
            floatx4 e00,e01,e10,e11,e20,e21,e30,e31;
            floatx4 q00,q01,q10,q11,q20,q21,q30,q31;
            ldc4x16o(e00,e01,e10,e11,e20,e21,e30,e31,
                     q00,q01,q10,q11,q20,q21,q30,q31,
                     pe0,pe1,pe2,pe3,pq0,pq1,pq2,pq3);
            floatx4 es0 = e00+e10+e20+e30, es1 = e01+e11+e21+e31;
            floatx4 qs0 = q00+q10+q20+q30, qs1 = q01+q11+q21+q31;
            int tok = t - 7 + wX;
            float ga = 0.f;
            floatx4 vv0 = {0,0,0,0}, vv1 = {0,0,0,0};
            if (tok >= 0) {
                ga = gammaB[b*Ln + tok] * invc;
                vv0 = *(const floatx4*)&vin[(size_t)(b*Ln + tok)*Dn + dX];
                vv1 = *(const floatx4*)&vin[(size_t)(b*Ln + tok)*Dn + dX + 4];
            }
            floatx4 u0 = ga*(es0 - vv0), u1 = ga*(es1 - vv1);
            *(floatx4*)&uv[wX*260 + dX]     = u0;
            *(floatx4*)&uv[wX*260 + dX + 4] = u1;
            *(floatx4*)&qv[wX*260 + dX]     = qs0;
            *(floatx4*)&qv[wX*260 + dX + 4] = qs1;
        }
        __syncthreads();

        // ---- L3: c = th.q + 0.5 K u  ;  rowsq recurrence + norm reduce
        {
#pragma unroll
            for (int qq = 0; qq < 8; ++qq) {
                int idx = qq*256 + tid;
                int w = idx >> 8, e = idx & 255;
                float sv = thv[e] * qv[w*260 + e];
#pragma unroll
                for (int w2 = 0; w2 < 8; ++w2)
                    sv += 0.5f * Kl[w*8 + w2] * uv[w2*260 + e];
                cv[w*260 + e] = sv;
            }
            float uu8[8], qq8[8];
#pragma unroll
            for (int w = 0; w < 8; ++w) { uu8[w] = uv[w*260 + tid]; qq8[w] = qv[w*260 + tid]; }
            float th_d = thv[tid];
            float cross = 0.f, quad = 0.f;
#pragma unroll
            for (int w = 0; w < 8; ++w) {
                cross += uu8[w] * qq8[w];
                float kk = 0.f;
#pragma unroll
                for (int w2 = 0; w2 < 8; ++w2) kk += Kl[w*8 + w2] * uu8[w2];
                quad += uu8[w] * kk;
            }
            float rq = th_d*th_d*rowsq_r + 2.f*th_d*cross + quad;
            rowsq_r = rq;
#pragma unroll
            for (int off = 32; off; off >>= 1) rq += __shfl_xor(rq, off);
            if (lane == 0) red[wid] = rq;
        }
        __syncthreads();

        // ---- L5: S column update (fp32 + bf16 mirror) ; T register update
        {
            int e = tid >> 2, d0s = (tid & 3) * 64;
            float kv8[8];
#pragma unroll
            for (int w = 0; w < 8; ++w) kv8[w] = kWA[w*260 + l0 + e];
#pragma unroll
            for (int c = 0; c < 16; ++c) {
                floatx4 sv = *(floatx4*)&Scol[e*260 + d0s + c*4];
                floatx4 tv = *(const floatx4*)&thv[d0s + c*4];
                sv = tv * sv;
#pragma unroll
                for (int w = 0; w < 8; ++w) {
                    floatx4 uvv = *(const floatx4*)&uv[w*260 + d0s + c*4];
                    sv += kv8[w] * uvv;
                }
                *(floatx4*)&Scol[e*260 + d0s + c*4] = sv;
                unsigned long long pk = packbf4(sv);
                *(unsigned long long*)(STbB +
                    (((size_t)e*528 + 2*(size_t)(d0s + c*4)) ^ (unsigned)((e&8)<<1))) = pk;
            }
            // T update in regs: T = thth*T + u c^T + c u^T
            int i = i0 + wid*16 + lme;
            float thi = thv[i];
            float ui8[8], ci8[8];
#pragma unroll
            for (int w = 0; w < 8; ++w) { ui8[w] = uv[w*260 + i]; ci8[w] = cv[w*260 + i]; }
#pragma unroll
            for (int kc = 0; kc < 8; ++kc) {
                int k0 = kc*32 + hi*8;
                floatx4 th0 = *(const floatx4*)&thv[k0];
                floatx4 th1 = *(const floatx4*)&thv[k0 + 4];
                floatx4 t0 = (thi * th0) * T_reg[kc*2+0];
                floatx4 t1 = (thi * th1) * T_reg[kc*2+1];
#pragma unroll
                for (int w = 0; w < 8; ++w) {
                    floatx4 uk0 = *(const floatx4*)&uv[w*260 + k0];
                    floatx4 uk1 = *(const floatx4*)&uv[w*260 + k0 + 4];
                    floatx4 ck0 = *(const floatx4*)&cv[w*260 + k0];
                    floatx4 ck1 = *(const floatx4*)&cv[w*260 + k0 + 4];
                    t0 += ui8[w]*ck0 + ci8[w]*uk0;
                    t1 += ui8[w]*ck1 + ci8[w]*uk1;
                }
                T_reg[kc*2+0] = t0;
                T_reg[kc*2+1] = t1;
            }
        }
        __syncthreads();

        // ---- L6: MFMA TS ; NS ; M update ; y  (+outM/outS at t=255)
        {
            floatx4 acc[4];
#pragma unroll
            for (int lt = 0; lt < 4; ++lt) acc[lt] = (floatx4){0.f,0.f,0.f,0.f};
#pragma unroll
            for (int kc = 0; kc < 8; ++kc) {
                BF8 ua; ua.u[0] = packbf4(T_reg[kc*2]); ua.u[1] = packbf4(T_reg[kc*2+1]);
                int kbyte = kc*64 + hi*16;
#pragma unroll
                for (int lt = 0; lt < 4; ++lt) {
                    int row = lt*16 + lme;
                    short8 bf = *(const short8*)(STbB +
                        (((size_t)row*528 + kbyte) ^ (unsigned)((row & 8) << 1)));
                    acc[lt] = __builtin_amdgcn_mfma_f32_16x16x32_bf16(ua.s8, bf, acc[lt], 0,0,0);
                }
            }
            float nsq = red[0] + red[1] + red[2] + red[3];
            float nrm = sqrtf(nsq) + 1e-7f;
            float inv_n = 1.f / nrm;
            float w1 = 1.5f * inv_n;
            float w3 = 0.5f * inv_n * inv_n * inv_n;
            float alv[4], etv[4], kvr[4];
#pragma unroll
            for (int g = 0; g < 4; ++g) {
                alv[g] = alphaB[(size_t)(b*Ln + t)*Dn + ibr + g];
                etv[g] = etaB[(size_t)(b*Ln + t)*Dn + ibr + g];
            }
#pragma unroll
            for (int lt = 0; lt < 4; ++lt) kvr[lt] = kWA[7*260 + l0 + lt*16 + lme];
            float py[4] = {0.f,0.f,0.f,0.f};
#pragma unroll
            for (int lt = 0; lt < 4; ++lt)
#pragma unroll
                for (int g = 0; g < 4; ++g) {
                    int l_loc = lt*16 + lme;
                    float s_il = Scol[l_loc*260 + ibr + g];
                    float ns = w1 * s_il - w3 * acc[lt][g];
                    float mn = alv[g] * M_reg[lt*4+g] - etv[g] * ns;
                    M_reg[lt*4+g] = mn;
                    py[g] += mn * kvr[lt];
                    if (t == Ln - 1)
                        outM[(size_t)(b*256 + ibr + g)*256 + l0 + l_loc] = mn;
                }
#pragma unroll
            for (int g = 0; g < 4; ++g) {
                py[g] += __shfl_xor(py[g], 1); py[g] += __shfl_xor(py[g], 2);
                py[g] += __shfl_xor(py[g], 4); py[g] += __shfl_xor(py[g], 8);
                if (lme == 0)
                    stc(&ysp[(size_t)s*BLD + (size_t)(b*Ln + t)*Dn + ibr + g], py[g]);
            }
        }

        // ---- L7: partials for t+1 (window(t+1) = kWA[w+1] / kNext)
        if (t < Ln - 1) {
            const int p2 = (t + 1) & 1;
#pragma unroll
            for (int w = 0; w < 8; ++w) {
                float pd[4] = {0.f,0.f,0.f,0.f};
#pragma unroll
                for (int lt = 0; lt < 4; ++lt) {
                    int li = l0 + lt*16 + lme;
                    float kv2 = (w < 7) ? kWA[(w+1)*260 + li] : kNext[li];
#pragma unroll
                    for (int g = 0; g < 4; ++g) pd[g] += M_reg[lt*4+g] * kv2;
                }
#pragma unroll
                for (int g = 0; g < 4; ++g) {
                    pd[g] += __shfl_xor(pd[g], 1); pd[g] += __shfl_xor(pd[g], 2);
                    pd[g] += __shfl_xor(pd[g], 4); pd[g] += __shfl_xor(pd[g], 8);
                }
                if (lme == 0) {
                    floatx4 pv = {pd[0], pd[1], pd[2], pd[3]};
                    stc4(&errp[(size_t)((s*2 + p2)*4 + b)*2048 + w*256 + ibr], pv);
                }
            }
            {
                int dq = i0 + (tid >> 2), eq0 = (tid & 3) * 16;
                float qpd[8] = {0,0,0,0,0,0,0,0};
                for (int j = 0; j < 16; ++j) {
                    int li = l0 + eq0 + j;
                    float sv = Scol[(eq0 + j)*260 + dq];
#pragma unroll
                    for (int w = 0; w < 8; ++w)
                        qpd[w] += sv * ((w < 7) ? kWA[(w+1)*260 + li] : kNext[li]);
                }
#pragma unroll
                for (int w = 0; w < 8; ++w) {
                    qpd[w] += __shfl_xor(qpd[w], 1); qpd[w] += __shfl_xor(qpd[w], 2);
                }
                if ((tid & 3) == 0)
#pragma unroll
                    for (int w = 0; w < 8; ++w)
                        stc(&qp[(size_t)((s*2 + p2)*4 + b)*2048 + w*256 + dq], qpd[w]);
            }
        } else if ((rem >> 2) == 0) {
            // outS: Scol -> row-major, coalesced float4 (only i0==0 group)
            for (int c = 0; c < 4; ++c) {
                float tb_[16];
#pragma unroll
                for (int j = 0; j < 16; ++j) tb_[j] = Scol[(c*16 + j)*260 + tid];
#pragma unroll
                for (int g2 = 0; g2 < 4; ++g2) {
                    floatx4 ov = {tb_[g2*4], tb_[g2*4+1], tb_[g2*4+2], tb_[g2*4+3]};
                    *(floatx4*)&outS[(size_t)(b*256 + tid)*256 + l0 + c*16 + g2*4] = ov;
                }
            }
        }
        grid_sync_b(bflags, rem, ++kbar);
    }
}

// -------------------------------------------------------------------------
extern "C" void kernel_launch(void* const* d_in, const int* in_sizes, int n_in,
                              void* d_out, int out_size, void* d_ws, size_t ws_size,
                              hipStream_t stream)
{
    const float* x       = (const float*)d_in[0];
    const float* k_al    = (const float*)d_in[1];
    const float* v       = (const float*)d_in[2];
    const float* M_prev  = (const float*)d_in[3];
    const float* S_prev  = (const float*)d_in[4];
    const float* poly    = (const float*)d_in[5];
    const float* alpha_W = (const float*)d_in[6];
    const float* alpha_b = (const float*)d_in[7];
    const float* eta_W   = (const float*)d_in[8];
    const float* eta_b   = (const float*)d_in[9];
    const float* theta_W = (const float*)d_in[10];
    const float* theta_b = (const float*)d_in[11];
    const float* gamma_W = (const float*)d_in[12];
    const float* gamma_b = (const float*)d_in[13];
    const float* out_W   = (const float*)d_in[14];
    const float* out_b   = (const float*)d_in[15];

    float* ws = (float*)d_ws;
    float* kphi    = ws;                    // 262144
    float* alphaB  = kphi   + BLD;          // 262144
    float* etaB    = alphaB + BLD;          // 262144
    float* thetaB  = etaB   + BLD;          // 262144
    float* gammaB  = thetaB + BLD;          // 1024
    float* Kall    = gammaB + Bn*Ln;        // 65536
    float* errp    = Kall   + Bn*Ln*64;     // 65536 (4 slots x 2 par x B x 8 x 256)
    float* qp      = errp   + 65536;        // 65536
    float* rsqp    = qp     + 65536;        // 4096
    float* ysp     = rsqp   + 4096;         // 4 x 262144
    unsigned* flags = (unsigned*)(ysp + 4*BLD);  // 2048 u32

    float* out_y = (float*)d_out;           // [B,L,D]
    float* outM  = out_y + BLD;             // [B,D,D]
    float* outS  = outM + BDD;              // [B,D,D]

    // precompute
    hipLaunchKernelGGL(kphi_gamma_kernel, dim3(256), dim3(256), 0, stream,
                       k_al, x, poly, gamma_W, gamma_b, kphi, gammaB);
    hipLaunchKernelGGL((gemm_act_kernel<1>), dim3(32, 4), dim3(256), 0, stream,
                       x, alpha_W, alpha_b, alphaB);
    hipLaunchKernelGGL((gemm_act_kernel<2>), dim3(32, 4), dim3(256), 0, stream,
                       x, eta_W, eta_b, etaB);
    hipLaunchKernelGGL((gemm_act_kernel<1>), dim3(32, 4), dim3(256), 0, stream,
                       x, theta_W, theta_b, thetaB);
    hipLaunchKernelGGL(kgram_kernel, dim3(Ln, Bn), dim3(64), 0, stream,
                       kphi, Kall);
    hipLaunchKernelGGL(prologue_kernel, dim3(2), dim3(256), 0, stream, flags);

    // persistent single-phase scan
    hipLaunchKernelGGL(scan_kernel, dim3(NBLK), dim3(256), 0, stream,
                       kphi, v, gammaB, alphaB, etaB, thetaB, Kall,
                       M_prev, S_prev, errp, qp, rsqp, ysp, flags,
                       outM, outS);

    // fold y slots, then out projection
    hipLaunchKernelGGL(ysum_kernel, dim3(256), dim3(256), 0, stream, ysp);
    hipLaunchKernelGGL((gemm_act_kernel<0>), dim3(32, 4), dim3(256), 0, stream,
                       ysp, out_W, out_b, out_y);
}

// Round 16
// 5326.218 us; speedup vs baseline: 1.6019x; 1.6019x over previous
//
#include <hip/hip_runtime.h>

// Problem constants
#define Bn 4
#define Ln 256
#define Dn 256
#define Wn 8
#define BLD (Bn*Ln*Dn)   // 262144
#define BDD (Bn*Dn*Dn)   // 262144

typedef float  floatx4 __attribute__((ext_vector_type(4)));
typedef short  short8  __attribute__((ext_vector_type(8)));

// bf16 pack (RNE)
__device__ __forceinline__ unsigned f2bf(float x) {
    unsigned u = __float_as_uint(x);
    return (u + 0x7FFFu + ((u >> 16) & 1u)) >> 16;
}
__device__ __forceinline__ unsigned long long packbf4(floatx4 v) {
    unsigned lo = f2bf(v[0]) | (f2bf(v[1]) << 16);
    unsigned hi = f2bf(v[2]) | (f2bf(v[3]) << 16);
    return (unsigned long long)lo | ((unsigned long long)hi << 32);
}
union BF8 { short8 s8; unsigned long long u[2]; };

// -------------------------------------------------------------------------
// kphi + gamma    [verified round 2]
// -------------------------------------------------------------------------
__global__ __launch_bounds__(256) void kphi_gamma_kernel(
    const float* __restrict__ k_al, const float* __restrict__ x,
    const float* __restrict__ poly, const float* __restrict__ gW,
    const float* __restrict__ gb, float* __restrict__ kphi,
    float* __restrict__ gamma)
{
    int wg = blockIdx.x, tid = threadIdx.x;
    int wave = tid >> 6, lane = tid & 63;
    int n = wg * 4 + wave;
    float gacc = 0.f;
#pragma unroll
    for (int c = 0; c < 4; ++c) {
        int e = lane + 64 * c;
        float kv = k_al[n * Dn + e];
        kphi[n * Dn + e] = poly[e] * kv + poly[Dn + e] * kv * kv;
        gacc += x[n * Dn + e] * gW[e];
    }
#pragma unroll
    for (int off = 32; off; off >>= 1) gacc += __shfl_xor(gacc, off);
    if (lane == 0) gamma[n] = 1.f / (1.f + expf(-(gacc + gb[0])));
}

// -------------------------------------------------------------------------
// tiled GEMM  [verified round 2]
// -------------------------------------------------------------------------
template <int ACT>
__global__ __launch_bounds__(256) void gemm_act_kernel(
    const float* __restrict__ In, const float* __restrict__ Wm,
    const float* __restrict__ bias, float* __restrict__ Out)
{
    __shared__ float ldsX[32 * 64];
    __shared__ float ldsW[64 * 65];
    int n0 = blockIdx.x * 32;
    int m0 = blockIdx.y * 64;
    int tid = threadIdx.x;
    float acc[8] = {0, 0, 0, 0, 0, 0, 0, 0};
    for (int j0 = 0; j0 < 256; j0 += 64) {
#pragma unroll
        for (int q = 0; q < 2; ++q) {
            int fi = tid + 256 * q; int row = fi >> 4; int c4 = (fi & 15) << 2;
            *(float4*)&ldsX[row * 64 + c4] =
                *(const float4*)&In[(n0 + row) * 256 + j0 + c4];
        }
#pragma unroll
        for (int q = 0; q < 4; ++q) {
            int fi = tid + 256 * q; int row = fi >> 4; int c4 = (fi & 15) << 2;
            float4 vv = *(const float4*)&Wm[(m0 + row) * 256 + j0 + c4];
            ldsW[(c4 + 0) * 65 + row] = vv.x;
            ldsW[(c4 + 1) * 65 + row] = vv.y;
            ldsW[(c4 + 2) * 65 + row] = vv.z;
            ldsW[(c4 + 3) * 65 + row] = vv.w;
        }
        __syncthreads();
        int m = tid & 63, ng = tid >> 6;
        for (int j = 0; j < 64; ++j) {
            float wv = ldsW[j * 65 + m];
#pragma unroll
            for (int r = 0; r < 8; ++r) acc[r] += ldsX[(ng * 8 + r) * 64 + j] * wv;
        }
        __syncthreads();
    }
    int m = tid & 63, ng = tid >> 6;
    float bv = bias[m0 + m];
#pragma unroll
    for (int r = 0; r < 8; ++r) {
        float vv = acc[r] + bv;
        if (ACT == 1) vv = 1.f / (1.f + expf(-vv));
        if (ACT == 2) vv = 0.1f / (1.f + expf(-vv));
        Out[(n0 + ng * 8 + r) * 256 + m0 + m] = vv;
    }
}

// -------------------------------------------------------------------------
// K-gram precompute   [verified round 8]
// -------------------------------------------------------------------------
__global__ __launch_bounds__(64) void kgram_kernel(
    const float* __restrict__ kphi, float* __restrict__ Kall)
{
    int t = blockIdx.x, b = blockIdx.y, tid = threadIdx.x;
    int wa = tid >> 3, wb = tid & 7;
    int ta = t - 7 + wa, tb = t - 7 + wb;
    float g = 0.f;
    if (ta >= 0 && tb >= 0) {
        const float* pa = &kphi[(b * Ln + ta) * Dn];
        const float* pb = &kphi[(b * Ln + tb) * Dn];
        for (int j = 0; j < Dn; j += 4) {
            floatx4 x1 = *(const floatx4*)&pa[j];
            floatx4 x2 = *(const floatx4*)&pb[j];
            g += x1[0]*x2[0] + x1[1]*x2[1] + x1[2]*x2[2] + x1[3]*x2[3];
        }
    }
    Kall[(b * Ln + t) * 64 + tid] = g;
}

// -------------------------------------------------------------------------
// prologue: working M,S into d_out; zero ys and errp
// -------------------------------------------------------------------------
__global__ __launch_bounds__(256) void prologue_kernel(
    const float* __restrict__ Mprev, const float* __restrict__ Sprev,
    float* __restrict__ M, float* __restrict__ S,
    float* __restrict__ ys, float* __restrict__ errp)
{
    int gidx = blockIdx.x * 256 + threadIdx.x;   // 0..65535
    ((float4*)M)[gidx] = ((const float4*)Mprev)[gidx];
    ((float4*)S)[gidx] = ((const float4*)Sprev)[gidx];
    float4 z = {0.f, 0.f, 0.f, 0.f};
    ((float4*)ys)[gidx] = z;
    if (gidx < 16384) ((float4*)errp)[gidx] = z;   // 65536 floats
}

// -------------------------------------------------------------------------
// T init: Tg0[b][i][l] = Sprev[b][i][:] . Sprev[b][l][:]  (bf16 MFMA)
// grid 64 = (b, i0, l0); each block one 64x64 tile.
// -------------------------------------------------------------------------
__global__ __launch_bounds__(256) void tinit_kernel(
    const float* __restrict__ Sprev, float* __restrict__ Tg0)
{
    const int wg = blockIdx.x, tid = threadIdx.x;
    const int b = wg >> 4, rem = wg & 15;
    const int i0 = (rem >> 2) * 64, l0 = (rem & 3) * 64;
    const int wid = tid >> 6, lane = tid & 63;
    const int lme = lane & 15, hi = lane >> 4;
    floatx4 acc[4];
#pragma unroll
    for (int lt = 0; lt < 4; ++lt) acc[lt] = (floatx4){0.f,0.f,0.f,0.f};
#pragma unroll
    for (int kc = 0; kc < 8; ++kc) {
        int kb2 = kc*32 + hi*8;
        floatx4 a0 = *(const floatx4*)&Sprev[(size_t)(b*256 + i0 + wid*16 + lme)*256 + kb2];
        floatx4 a1 = *(const floatx4*)&Sprev[(size_t)(b*256 + i0 + wid*16 + lme)*256 + kb2 + 4];
        BF8 ua; ua.u[0] = packbf4(a0); ua.u[1] = packbf4(a1);
#pragma unroll
        for (int lt = 0; lt < 4; ++lt) {
            int brow = l0 + lt*16 + lme;
            floatx4 b0 = *(const floatx4*)&Sprev[(size_t)(b*256 + brow)*256 + kb2];
            floatx4 b1 = *(const floatx4*)&Sprev[(size_t)(b*256 + brow)*256 + kb2 + 4];
            BF8 ub; ub.u[0] = packbf4(b0); ub.u[1] = packbf4(b1);
            acc[lt] = __builtin_amdgcn_mfma_f32_16x16x32_bf16(ua.s8, ub.s8, acc[lt], 0,0,0);
        }
    }
#pragma unroll
    for (int lt = 0; lt < 4; ++lt)
#pragma unroll
        for (int g = 0; g < 4; ++g)
            Tg0[(size_t)(b*256 + i0 + wid*16 + (hi<<2) + g)*256 + l0 + lt*16 + lme]
                = acc[lt][g];
}

// -------------------------------------------------------------------------
// err0: errp parity-0 partials for t=0 (window has only w=7 = token 0)
// grid 64 = (b, rem -> i0,l0 tile of Mprev)
// -------------------------------------------------------------------------
__global__ __launch_bounds__(256) void err0_kernel(
    const float* __restrict__ kphi, const float* __restrict__ Mprev,
    float* __restrict__ errp)
{
    __shared__ float kW2[Wn * 256];
    const int wg = blockIdx.x, tid = threadIdx.x;
    const int b = wg >> 4, rem = wg & 15;
    const int s = rem & 3;
    const int i0 = (rem >> 2) * 64, l0 = (rem & 3) * 64;
    const int wid = tid >> 6, lane = tid & 63;
    const int lme = lane & 15, hi = lane >> 4;
    const int ibr = i0 + wid * 16 + (hi << 2);
#pragma unroll
    for (int q = 0; q < 2; ++q) {
        int w = q*4 + (tid >> 6);
        int c4 = (tid & 63) << 2;
        floatx4 kv = {0.f,0.f,0.f,0.f};
        if (w == 7) kv = *(const floatx4*)&kphi[(size_t)(b*Ln)*Dn + c4];
        *(floatx4*)&kW2[w*256 + c4] = kv;
    }
    __syncthreads();
    float M_reg[16];
#pragma unroll
    for (int lt = 0; lt < 4; ++lt)
#pragma unroll
        for (int g = 0; g < 4; ++g)
            M_reg[lt*4+g] = Mprev[(size_t)(b*256 + ibr + g)*256 + l0 + lt*16 + lme];
#pragma unroll
    for (int w = 0; w < 8; ++w) {
        float pd[4] = {0.f,0.f,0.f,0.f};
#pragma unroll
        for (int lt = 0; lt < 4; ++lt) {
            float kv2 = kW2[w*256 + l0 + lt*16 + lme];
#pragma unroll
            for (int g = 0; g < 4; ++g) pd[g] += M_reg[lt*4+g] * kv2;
        }
#pragma unroll
        for (int g = 0; g < 4; ++g) {
            pd[g] += __shfl_xor(pd[g], 1); pd[g] += __shfl_xor(pd[g], 2);
            pd[g] += __shfl_xor(pd[g], 4); pd[g] += __shfl_xor(pd[g], 8);
        }
        if (lme == 0)
#pragma unroll
            for (int g = 0; g < 4; ++g)
                errp[(size_t)((s*2 + 0)*4 + b)*2048 + w*256 + ibr + g] = pd[g];
    }
}

// -------------------------------------------------------------------------
// PHASE A kernel (per step t): kernel boundary = sync with C_{t-1}.
// grid 64 = (b, rem=strip). Plain cached loads/stores only.
// -------------------------------------------------------------------------
__global__ __launch_bounds__(256) void phaseA_kernel(
    const float* __restrict__ kphi, const float* __restrict__ vin,
    const float* __restrict__ gammaB, const float* __restrict__ thetaB,
    float* __restrict__ Sg, unsigned short* __restrict__ STg,
    float* __restrict__ u_buf, float* __restrict__ a_buf,
    const float* __restrict__ errp, float* __restrict__ normp, int t)
{
    __shared__ float usl[Wn * 16];
    __shared__ float kWA[Wn * 260];
    __shared__ float Sl[16 * 260];
    __shared__ float wsum[4];
    const int wg = blockIdx.x, tid = threadIdx.x;
    const int b = wg >> 4, rem = wg & 15;
    const int d0 = rem << 4;
    const int wid = tid >> 6, lane = tid & 63;
    const int r = tid >> 4, m = tid & 15;
    const int e0 = m * 16;
    const int cwin = (t + 1 < Wn) ? (t + 1) : Wn;
    const float invc = 1.f / (float)cwin;
    const int p = t & 1;

    if (tid < 128) {
        int w_a = tid >> 4, rr_a = tid & 15;
        float ep = 0.f;
#pragma unroll
        for (int sl = 0; sl < 4; ++sl)
            ep += errp[(size_t)((sl*2 + p)*4 + b)*2048 + w_a*256 + d0 + rr_a];
        int tok = t - 7 + w_a;
        float uu = 0.f;
        if (tok >= 0)
            uu = gammaB[b*Ln + tok] * invc *
                 (ep - vin[(size_t)(b*Ln + tok)*Dn + d0 + rr_a]);
        usl[w_a*16 + rr_a] = uu;
        u_buf[(size_t)(b*8 + w_a)*256 + d0 + rr_a] = uu;
    } else {
        int idx = tid - 128;
        int w = idx >> 4, seg = idx & 15;
        int tk = t - 7 + w;
#pragma unroll
        for (int q = 0; q < 4; ++q) {
            floatx4 kv = {0.f,0.f,0.f,0.f};
            if (tk >= 0)
                kv = *(const floatx4*)&kphi[(size_t)(b*Ln + tk)*Dn + seg*16 + q*4];
            *(floatx4*)&kWA[w*260 + seg*16 + q*4] = kv;
        }
    }
    __syncthreads();

    // load S strip (exclusive owner), q dots, a = theta*q
    floatx4 S_reg[4];
#pragma unroll
    for (int cq = 0; cq < 4; ++cq)
        S_reg[cq] = *(const floatx4*)&Sg[(size_t)(b*256 + d0 + r)*256 + e0 + cq*4];
    {
        float qw[8] = {0,0,0,0,0,0,0,0};
#pragma unroll
        for (int cq = 0; cq < 4; ++cq) {
            floatx4 sv = S_reg[cq];
#pragma unroll
            for (int w = 0; w < 8; ++w) {
                floatx4 kv = *(const floatx4*)&kWA[w*260 + e0 + cq*4];
                qw[w] += sv[0]*kv[0] + sv[1]*kv[1] + sv[2]*kv[2] + sv[3]*kv[3];
            }
        }
#pragma unroll
        for (int w = 0; w < 8; ++w) {
            qw[w] += __shfl_xor(qw[w], 1); qw[w] += __shfl_xor(qw[w], 2);
            qw[w] += __shfl_xor(qw[w], 4); qw[w] += __shfl_xor(qw[w], 8);
        }
        if (m < 8) {
            float th = thetaB[(size_t)(b*Ln + t)*Dn + d0 + r];
            a_buf[(size_t)(b*8 + m)*256 + d0 + r] = th * qw[m];
        }
    }
    // S update + norm partial
    {
        float th = thetaB[(size_t)(b*Ln + t)*Dn + d0 + r];
        float uu[8];
#pragma unroll
        for (int w = 0; w < 8; ++w) uu[w] = usl[w*16 + r];
        float sumsq = 0.f;
#pragma unroll
        for (int cq = 0; cq < 4; ++cq) {
            floatx4 sv = th * S_reg[cq];
#pragma unroll
            for (int w = 0; w < 8; ++w) {
                floatx4 kv = *(const floatx4*)&kWA[w*260 + e0 + cq*4];
                sv += uu[w] * kv;
            }
            S_reg[cq] = sv;
            sumsq += sv[0]*sv[0] + sv[1]*sv[1] + sv[2]*sv[2] + sv[3]*sv[3];
        }
#pragma unroll
        for (int off = 32; off; off >>= 1) sumsq += __shfl_xor(sumsq, off);
        if (lane == 0) wsum[wid] = sumsq;
    }
    // write S back (in place) + export S^T bf16 via LDS transpose
    {
#pragma unroll
        for (int cq = 0; cq < 4; ++cq) {
            *(floatx4*)&Sg[(size_t)(b*256 + d0 + r)*256 + e0 + cq*4] = S_reg[cq];
            *(floatx4*)&Sl[r*260 + e0 + cq*4] = S_reg[cq];
        }
        __syncthreads();
        int l = tid;
        unsigned dw[8];
#pragma unroll
        for (int j = 0; j < 8; ++j)
            dw[j] = f2bf(Sl[(2*j)*260 + l]) | (f2bf(Sl[(2*j+1)*260 + l]) << 16);
        float4 p0 = { __uint_as_float(dw[0]), __uint_as_float(dw[1]),
                      __uint_as_float(dw[2]), __uint_as_float(dw[3]) };
        float4 p1 = { __uint_as_float(dw[4]), __uint_as_float(dw[5]),
                      __uint_as_float(dw[6]), __uint_as_float(dw[7]) };
        char* dstp = (char*)STg + ((size_t)(b*256 + l)*256 + d0)*2;
        *(float4*)dstp = p0;
        *(float4*)(dstp + 16) = p1;
        if (tid == 0)
            normp[b*16 + rem] = wsum[0] + wsum[1] + wsum[2] + wsum[3];
    }
}

// -------------------------------------------------------------------------
// PHASE C kernel (per step t): kernel boundary = sync with A_t.
// grid 64 = (b, rem -> i0,l0). T parity double-buffered in global.
// -------------------------------------------------------------------------
__global__ __launch_bounds__(256) void phaseC_kernel(
    const float* __restrict__ kphi, const float* __restrict__ alphaB,
    const float* __restrict__ etaB, const float* __restrict__ thetaB,
    const float* __restrict__ Kall,
    const unsigned short* __restrict__ STg,
    const float* __restrict__ u_buf, const float* __restrict__ a_buf,
    const float* __restrict__ normp,
    const float* __restrict__ Tin, float* __restrict__ Tout,
    float* __restrict__ Mg, float* __restrict__ ys,
    float* __restrict__ errp, int t)
{
    __shared__ float smem[8448 + 2048*3 + 256 + 256 + 64 + 16 + 2048];
    char*  STb  = (char*)smem;            // bf16 [64][264] swizzled
    float* uvp  = smem + 8448;
    float* avp  = smem + 10496;
    float* cvp  = smem + 12544;
    float* thv  = smem + 14592;
    float* kT   = smem + 14848;
    float* Kl   = smem + 15104;
    float* nrml = smem + 15168;
    float* kW2  = smem + 15184;

    const int wg = blockIdx.x, tid = threadIdx.x;
    const int b = wg >> 4, rem = wg & 15;
    const int s = rem & 3;
    const int i0 = (rem >> 2) * 64, l0 = (rem & 3) * 64;
    const int wid = tid >> 6, lane = tid & 63;
    const int lme = lane & 15, hi = lane >> 4;
    const int ibr = i0 + wid * 16 + (hi << 2);

    // c1: stage ST panel + u + a + norm + theta + kT + Kl + kW2 (plain loads)
    {
        int lq = tid >> 2, kq = (tid & 3) * 64;
        const char* src = (const char*)STg + ((size_t)(b*256 + l0 + lq)*256 + kq)*2;
        size_t rb0 = (size_t)lq*528 + (size_t)kq*2;
        unsigned swz = (unsigned)((lq & 8) << 1);
#pragma unroll
        for (int q = 0; q < 8; ++q) {
            float4 vv = *(const float4*)(src + q*16);
            *(float4*)(STb + ((rb0 + q*16) ^ swz)) = vv;
        }
        *(floatx4*)&uvp[tid*8]     = *(const floatx4*)&u_buf[(size_t)b*2048 + tid*8];
        *(floatx4*)&uvp[tid*8 + 4] = *(const floatx4*)&u_buf[(size_t)b*2048 + tid*8 + 4];
        *(floatx4*)&avp[tid*8]     = *(const floatx4*)&a_buf[(size_t)b*2048 + tid*8];
        *(floatx4*)&avp[tid*8 + 4] = *(const floatx4*)&a_buf[(size_t)b*2048 + tid*8 + 4];
        if (tid < 16) nrml[tid] = normp[b*16 + tid];
        if (tid < 64) {
            *(floatx4*)&thv[tid*4] = *(const floatx4*)&thetaB[(size_t)(b*Ln + t)*Dn + tid*4];
            *(floatx4*)&kT[tid*4]  = *(const floatx4*)&kphi[(size_t)(b*Ln + t)*Dn + tid*4];
        }
        if (tid < 16)
            *(floatx4*)&Kl[tid*4] = *(const floatx4*)&Kall[(size_t)(b*Ln + t)*64 + tid*4];
        if (t < Ln - 1) {
#pragma unroll
            for (int q = 0; q < 2; ++q) {
                int w = q*4 + (tid >> 6);
                int c4 = (tid & 63) << 2;
                int tk = t + 1 - 7 + w;
                floatx4 kv = {0.f,0.f,0.f,0.f};
                if (tk >= 0) kv = *(const floatx4*)&kphi[(size_t)(b*Ln + tk)*Dn + c4];
                *(floatx4*)&kW2[w*256 + c4] = kv;
            }
        }
    }
    __syncthreads();

    // c2: c = a + 0.5 G u
#pragma unroll
    for (int q = 0; q < 8; ++q) {
        int idx = q*256 + tid;
        int w = idx >> 8, e = idx & 255;
        float sv = avp[idx];
#pragma unroll
        for (int w2 = 0; w2 < 8; ++w2)
            sv += 0.5f * Kl[w*8 + w2] * uvp[w2*256 + e];
        cvp[idx] = sv;
    }
    __syncthreads();

    // load T panel rows (A-frag layout) + update: T = thth*T + uc^T + cu^T
    floatx4 T_reg[16];
    {
        const float* Trow = &Tin[(size_t)(b*256 + i0 + wid*16 + lme)*256];
        int i = i0 + wid*16 + lme;
        float thi = thv[i];
        float ui8[8], ci8[8];
#pragma unroll
        for (int w = 0; w < 8; ++w) { ui8[w] = uvp[w*256 + i]; ci8[w] = cvp[w*256 + i]; }
#pragma unroll
        for (int kc = 0; kc < 8; ++kc) {
            int k0 = kc*32 + hi*8;
            floatx4 t0 = *(const floatx4*)&Trow[k0];
            floatx4 t1 = *(const floatx4*)&Trow[k0 + 4];
            floatx4 th0 = *(const floatx4*)&thv[k0];
            floatx4 th1 = *(const floatx4*)&thv[k0 + 4];
            t0 = (thi * th0) * t0;
            t1 = (thi * th1) * t1;
#pragma unroll
            for (int w = 0; w < 8; ++w) {
                floatx4 uk0 = *(const floatx4*)&uvp[w*256 + k0];
                floatx4 uk1 = *(const floatx4*)&uvp[w*256 + k0 + 4];
                floatx4 ck0 = *(const floatx4*)&cvp[w*256 + k0];
                floatx4 ck1 = *(const floatx4*)&cvp[w*256 + k0 + 4];
                t0 += ui8[w]*ck0 + ci8[w]*uk0;
                t1 += ui8[w]*ck1 + ci8[w]*uk1;
            }
            T_reg[kc*2+0] = t0;
            T_reg[kc*2+1] = t1;
        }
        if (s == 0) {   // exclusive writer of this panel into the parity^1 buffer
            float* Torow = &Tout[(size_t)(b*256 + i0 + wid*16 + lme)*256];
#pragma unroll
            for (int kc = 0; kc < 8; ++kc) {
                *(floatx4*)&Torow[kc*32 + hi*8]     = T_reg[kc*2+0];
                *(floatx4*)&Torow[kc*32 + hi*8 + 4] = T_reg[kc*2+1];
            }
        }
    }

    // c5: MFMA TS tile
    floatx4 acc[4];
#pragma unroll
    for (int lt = 0; lt < 4; ++lt) acc[lt] = (floatx4){0.f,0.f,0.f,0.f};
#pragma unroll
    for (int kc = 0; kc < 8; ++kc) {
        BF8 ua; ua.u[0] = packbf4(T_reg[kc*2]); ua.u[1] = packbf4(T_reg[kc*2+1]);
        int kbyte = kc*64 + hi*16;
#pragma unroll
        for (int lt = 0; lt < 4; ++lt) {
            int row = lt*16 + lme;
            short8 bf = *(const short8*)(STb +
                (((size_t)row*528 + kbyte) ^ (unsigned)((row & 8) << 1)));
            acc[lt] = __builtin_amdgcn_mfma_f32_16x16x32_bf16(ua.s8, bf, acc[lt], 0,0,0);
        }
    }

    // c6: NS, M update (in place, exclusive tile), y atomics
    {
        float nsq = 0.f;
#pragma unroll
        for (int q = 0; q < 16; ++q) nsq += nrml[q];
        float nrm = sqrtf(nsq) + 1e-7f;
        float inv_n = 1.f / nrm;
        float w1 = 1.5f * inv_n;
        float w3 = 0.5f * inv_n * inv_n * inv_n;
        float alv[4], etv[4], kvr[4], M_reg[16];
#pragma unroll
        for (int g = 0; g < 4; ++g) {
            alv[g] = alphaB[(size_t)(b*Ln + t)*Dn + ibr + g];
            etv[g] = etaB[(size_t)(b*Ln + t)*Dn + ibr + g];
        }
#pragma unroll
        for (int lt = 0; lt < 4; ++lt) kvr[lt] = kT[l0 + lt*16 + lme];
#pragma unroll
        for (int lt = 0; lt < 4; ++lt)
#pragma unroll
            for (int g = 0; g < 4; ++g)
                M_reg[lt*4+g] = Mg[(size_t)(b*256 + ibr + g)*256 + l0 + lt*16 + lme];
        float py[4] = {0.f,0.f,0.f,0.f};
#pragma unroll
        for (int lt = 0; lt < 4; ++lt)
#pragma unroll
            for (int g = 0; g < 4; ++g) {
                int l_loc = lt*16 + lme;
                unsigned short sb = *(const unsigned short*)(STb +
                    (((size_t)l_loc*528 + (size_t)(ibr + g)*2) ^ (unsigned)((l_loc & 8) << 1)));
                float s_il = __uint_as_float(((unsigned)sb) << 16);
                float ns = w1 * s_il - w3 * acc[lt][g];
                float mn = alv[g] * M_reg[lt*4+g] - etv[g] * ns;
                M_reg[lt*4+g] = mn;
                py[g] += mn * kvr[lt];
                Mg[(size_t)(b*256 + ibr + g)*256 + l0 + l_loc] = mn;
            }
#pragma unroll
        for (int g = 0; g < 4; ++g) {
            py[g] += __shfl_xor(py[g], 1); py[g] += __shfl_xor(py[g], 2);
            py[g] += __shfl_xor(py[g], 4); py[g] += __shfl_xor(py[g], 8);
            if (lme == 0) atomicAdd(&ys[(size_t)(b*Ln + t)*Dn + ibr + g], py[g]);
        }

        // c7: next-step err partials -> parity (t+1)&1 slot s (plain stores)
        if (t < Ln - 1) {
            const int p2 = (t + 1) & 1;
#pragma unroll
            for (int w = 0; w < 8; ++w) {
                float pd[4] = {0.f,0.f,0.f,0.f};
#pragma unroll
                for (int lt = 0; lt < 4; ++lt) {
                    float kv2 = kW2[w*256 + l0 + lt*16 + lme];
#pragma unroll
                    for (int g = 0; g < 4; ++g) pd[g] += M_reg[lt*4+g] * kv2;
                }
#pragma unroll
                for (int g = 0; g < 4; ++g) {
                    pd[g] += __shfl_xor(pd[g], 1); pd[g] += __shfl_xor(pd[g], 2);
                    pd[g] += __shfl_xor(pd[g], 4); pd[g] += __shfl_xor(pd[g], 8);
                }
                if (lme == 0)
#pragma unroll
                    for (int g = 0; g < 4; ++g)
                        errp[(size_t)((s*2 + p2)*4 + b)*2048 + w*256 + ibr + g] = pd[g];
            }
        }
    }
}

// -------------------------------------------------------------------------
extern "C" void kernel_launch(void* const* d_in, const int* in_sizes, int n_in,
                              void* d_out, int out_size, void* d_ws, size_t ws_size,
                              hipStream_t stream)
{
    const float* x       = (const float*)d_in[0];
    const float* k_al    = (const float*)d_in[1];
    const float* v       = (const float*)d_in[2];
    const float* M_prev  = (const float*)d_in[3];
    const float* S_prev  = (const float*)d_in[4];
    const float* poly    = (const float*)d_in[5];
    const float* alpha_W = (const float*)d_in[6];
    const float* alpha_b = (const float*)d_in[7];
    const float* eta_W   = (const float*)d_in[8];
    const float* eta_b   = (const float*)d_in[9];
    const float* theta_W = (const float*)d_in[10];
    const float* theta_b = (const float*)d_in[11];
    const float* gamma_W = (const float*)d_in[12];
    const float* gamma_b = (const float*)d_in[13];
    const float* out_W   = (const float*)d_in[14];
    const float* out_b   = (const float*)d_in[15];

    float* ws = (float*)d_ws;
    float* kphi    = ws;                    // 262144
    float* alphaB  = kphi   + BLD;          // 262144
    float* etaB    = alphaB + BLD;          // 262144
    float* thetaB  = etaB   + BLD;          // 262144
    float* gammaB  = thetaB + BLD;          // 1024
    float* Kall    = gammaB + Bn*Ln;        // 65536
    float* STg_f   = Kall   + Bn*Ln*64;     // 131072 (bf16 [B][256][256])
    float* u_bufp  = STg_f  + 131072;       // 8192
    float* a_bufp  = u_bufp + Bn*Wn*Dn;     // 8192
    float* errp    = a_bufp + Bn*Wn*Dn;     // 65536 (4 slots x 2 parity)
    float* normp   = errp   + 65536;        // 64
    float* ysb     = normp  + 64;           // 262144
    float* Tg0     = ysb    + BLD;          // 262144
    float* Tg1     = Tg0    + BDD;          // 262144
    // total ~8.5 MB (< 9.5 MB proven in round 9)

    float* out_y = (float*)d_out;           // [B,L,D]
    float* outM  = out_y + BLD;             // [B,D,D] working M, final in place
    float* outS  = outM + BDD;              // [B,D,D] working S, final in place

    // precompute
    hipLaunchKernelGGL(kphi_gamma_kernel, dim3(256), dim3(256), 0, stream,
                       k_al, x, poly, gamma_W, gamma_b, kphi, gammaB);
    hipLaunchKernelGGL((gemm_act_kernel<1>), dim3(32, 4), dim3(256), 0, stream,
                       x, alpha_W, alpha_b, alphaB);
    hipLaunchKernelGGL((gemm_act_kernel<2>), dim3(32, 4), dim3(256), 0, stream,
                       x, eta_W, eta_b, etaB);
    hipLaunchKernelGGL((gemm_act_kernel<1>), dim3(32, 4), dim3(256), 0, stream,
                       x, theta_W, theta_b, thetaB);
    hipLaunchKernelGGL(kgram_kernel, dim3(Ln, Bn), dim3(64), 0, stream,
                       kphi, Kall);
    hipLaunchKernelGGL(prologue_kernel, dim3(256), dim3(256), 0, stream,
                       M_prev, S_prev, outM, outS, ysb, errp);
    hipLaunchKernelGGL(tinit_kernel, dim3(64), dim3(256), 0, stream,
                       S_prev, Tg0);
    hipLaunchKernelGGL(err0_kernel, dim3(64), dim3(256), 0, stream,
                       kphi, M_prev, errp);

    // per-step: 2 kernels; kernel boundaries provide grid-wide sync
    for (int t = 0; t < Ln; ++t) {
        float* Tin  = (t & 1) ? Tg1 : Tg0;
        float* Tout = (t & 1) ? Tg0 : Tg1;
        hipLaunchKernelGGL(phaseA_kernel, dim3(64), dim3(256), 0, stream,
                           kphi, v, gammaB, thetaB, outS,
                           (unsigned short*)STg_f, u_bufp, a_bufp,
                           errp, normp, t);
        hipLaunchKernelGGL(phaseC_kernel, dim3(64), dim3(256), 0, stream,
                           kphi, alphaB, etaB, thetaB, Kall,
                           (const unsigned short*)STg_f, u_bufp, a_bufp, normp,
                           Tin, Tout, outM, ysb, errp, t);
    }

    // out projection
    hipLaunchKernelGGL((gemm_act_kernel<0>), dim3(32, 4), dim3(256), 0, stream,
                       ysb, out_W, out_b, out_y);
}